// Round 2
// baseline (493.857 us; speedup 1.0000x reference)
//
#include <hip/hip_runtime.h>
#include <hip/hip_bf16.h>

typedef __attribute__((ext_vector_type(8))) short short8;   // 8 bf16 in 4 VGPRs
typedef __attribute__((ext_vector_type(4))) float floatx4;

__device__ __forceinline__ floatx4 mfma_bf16(short8 a, short8 b, floatx4 c) {
  return __builtin_amdgcn_mfma_f32_16x16x32_bf16(a, b, c, 0, 0, 0);
}

// convert 8 contiguous fp32 -> 8 bf16 (one 16B store)
__device__ __forceinline__ void cvt8_store(const float* __restrict__ src,
                                           __hip_bfloat16* __restrict__ dst) {
  float4 a = *(const float4*)src;
  float4 b = *(const float4*)(src + 4);
  __hip_bfloat16 t[8];
  t[0] = __float2bfloat16(a.x); t[1] = __float2bfloat16(a.y);
  t[2] = __float2bfloat16(a.z); t[3] = __float2bfloat16(a.w);
  t[4] = __float2bfloat16(b.x); t[5] = __float2bfloat16(b.y);
  t[6] = __float2bfloat16(b.z); t[7] = __float2bfloat16(b.w);
  *(uint4*)dst = *(const uint4*)t;
}

// ---------------- prep: rows 0..2047 -> Xs (gathered LSTM inputs, bf16)
//                  rows 2048..4095 -> WhhB (W_hh converted to bf16)
__global__ __launch_bounds__(256) void prep(
    const float* __restrict__ feat,   // [64,512] fp32
    const int* __restrict__ caps,     // [64,32] int32 (int64 tolerated via sniff)
    const float* __restrict__ emb,    // [10000,512] fp32
    const float* __restrict__ Whh,    // [2048,512] fp32
    __hip_bfloat16* __restrict__ Xs,
    __hip_bfloat16* __restrict__ WhhB) {
  int tid = blockIdx.x * 256 + threadIdx.x;   // 262144 threads
  int r = tid >> 6;
  int ch = (tid & 63) * 8;
  const float* src;
  __hip_bfloat16* dst;
  if (r < 2048) {
    int t = r >> 6, b = r & 63;
    // int64 captions would have zero high words at odd int32 indices
    bool i64 = (caps[1] == 0) & (caps[3] == 0) & (caps[5] == 0) & (caps[7] == 0) &
               (caps[9] == 0) & (caps[11] == 0) & (caps[13] == 0);
    if (t == 0) {
      src = feat + (size_t)b * 512 + ch;
    } else {
      int idx = i64 ? caps[(size_t)(b * 32 + t) * 2] : caps[b * 32 + t];
      idx = idx < 0 ? 0 : (idx > 9999 ? 9999 : idx);
      src = emb + (size_t)idx * 512 + ch;
    }
    dst = Xs + (size_t)r * 512 + ch;
  } else {
    int rr = r - 2048;
    src = Whh + (size_t)rr * 512 + ch;
    dst = WhhB + (size_t)rr * 512 + ch;
  }
  cvt8_store(src, dst);
}

// ---------------- NT GEMM: C[M x N] = A[M x 512](bf16) * B[N x 512]^T(fp32->bf16) + bias
// mode 0: outF[row*ldc+col] = acc + b1[col] + b2[col]         (x_proj, row = t*64+b)
// mode 1: outF[((row&63)*32+(row>>6))*ldc+col] = acc + b1[col]  (logits [B,T,V])
__global__ __launch_bounds__(256) void gemm_nt(
    const __hip_bfloat16* __restrict__ A,
    const float* __restrict__ Bf,
    const float* __restrict__ b1,
    const float* __restrict__ b2,      // may be null
    float* __restrict__ outF,
    int Nrows, int ldc, int mode) {
  const int K = 512;
  __shared__ __align__(16) __hip_bfloat16 As[128 * 32];
  __shared__ __align__(16) __hip_bfloat16 Bs[128 * 32];
  const int tid = threadIdx.x;
  const int ib = blockIdx.x, jb = blockIdx.y;   // x = M-tile so same jb spreads over XCDs
  const int w = tid >> 6, l = tid & 63, lr = l & 15, lq = l >> 4;
  const int wr = (w & 1) * 64, wc = (w >> 1) * 64;
  floatx4 acc[4][4] = {};
  for (int kt = 0; kt < 16; ++kt) {
    const int k0 = kt * 32;
#pragma unroll
    for (int it = 0; it < 2; ++it) {
      int flat = it * 256 + tid;       // 0..511
      int row = flat >> 2;             // 0..127
      int c8 = (flat & 3) * 8;         // 0,8,16,24
      uint4 av = *(const uint4*)(A + (size_t)(ib * 128 + row) * K + k0 + c8);
      int rb = jb * 128 + row;
      if (rb > Nrows - 1) rb = Nrows - 1;   // clamp N=10000 tail (dup reads, cols guarded)
      *(uint4*)(As + flat * 8) = av;
      cvt8_store(Bf + (size_t)rb * K + k0 + c8, Bs + flat * 8);
    }
    __syncthreads();
    short8 af[4], bfr[4];
#pragma unroll
    for (int mt = 0; mt < 4; ++mt)
      af[mt] = *(const short8*)(As + (wr + mt * 16 + lr) * 32 + lq * 8);
#pragma unroll
    for (int nt = 0; nt < 4; ++nt)
      bfr[nt] = *(const short8*)(Bs + (wc + nt * 16 + lr) * 32 + lq * 8);
#pragma unroll
    for (int mt = 0; mt < 4; ++mt)
#pragma unroll
      for (int nt = 0; nt < 4; ++nt)
        acc[mt][nt] = mfma_bf16(af[mt], bfr[nt], acc[mt][nt]);
    __syncthreads();
  }
#pragma unroll
  for (int mt = 0; mt < 4; ++mt) {
#pragma unroll
    for (int nt = 0; nt < 4; ++nt) {
      int col = jb * 128 + wc + nt * 16 + lr;
      if (col < Nrows) {
        float bias = b1[col] + (b2 ? b2[col] : 0.f);
#pragma unroll
        for (int r = 0; r < 4; ++r) {
          int row = ib * 128 + wr + mt * 16 + lq * 4 + r;
          size_t orow = mode ? (size_t)((row & 63) * 32 + (row >> 6)) : (size_t)row;
          outF[orow * ldc + col] = acc[mt][nt][r] + bias;
        }
      }
    }
  }
}

// ---------------- persistent LSTM: 64 blocks (4 b-groups x 16 u-groups), 32 steps,
// agent-scope grid barrier between steps (ACQ_REL flushes/invalidates per-XCD L2).
__device__ __forceinline__ void grid_barrier(unsigned* cnt, unsigned target) {
  __syncthreads();
  if (threadIdx.x == 0) {
    __hip_atomic_fetch_add(cnt, 1u, __ATOMIC_ACQ_REL, __HIP_MEMORY_SCOPE_AGENT);
    while (__hip_atomic_load(cnt, __ATOMIC_ACQUIRE, __HIP_MEMORY_SCOPE_AGENT) < target)
      __builtin_amdgcn_s_sleep(2);
  }
  __syncthreads();
}

__global__ __launch_bounds__(256) void lstm_seq(
    const float* __restrict__ xp,            // [32][64][2048] fp32 (includes biases)
    const __hip_bfloat16* __restrict__ Whh,  // [2048][512] bf16 copy
    __hip_bfloat16* __restrict__ hseq,       // [32][64][512] bf16
    unsigned* __restrict__ bar) {
  const int bg = blockIdx.x >> 4;   // 0..3  (16 batch rows each)
  const int ug = blockIdx.x & 15;   // 0..15 (32 hidden units each)
  const int tid = threadIdx.x;
  const int w = tid >> 6, l = tid & 63, lr = l & 15, lq = l >> 4;
  __shared__ float gbuf[4][16][32];           // [gate][b_local][u_local]
  float cst[2] = {0.f, 0.f};
  // wave w computes gate w for units ug*32..+31 (two 16-wide MFMA col-tiles)
  const __hip_bfloat16* w0 = Whh + (size_t)(w * 512 + ug * 32 + lr) * 512;
  const __hip_bfloat16* w1 = Whh + (size_t)(w * 512 + ug * 32 + 16 + lr) * 512;
  for (int t = 0; t < 32; ++t) {
    floatx4 a0 = {}, a1 = {};
    if (t > 0) {
      const __hip_bfloat16* hp =
          hseq + (size_t)((t - 1) * 64 + bg * 16 + lr) * 512 + lq * 8;
#pragma unroll
      for (int kk = 0; kk < 16; ++kk) {
        short8 av = *(const short8*)(hp + kk * 32);
        short8 b0 = *(const short8*)(w0 + kk * 32 + lq * 8);
        short8 b1 = *(const short8*)(w1 + kk * 32 + lq * 8);
        a0 = mfma_bf16(av, b0, a0);
        a1 = mfma_bf16(av, b1, a1);
      }
    }
#pragma unroll
    for (int r = 0; r < 4; ++r) {
      gbuf[w][lq * 4 + r][lr] = a0[r];
      gbuf[w][lq * 4 + r][16 + lr] = a1[r];
    }
    __syncthreads();
#pragma unroll
    for (int s2 = 0; s2 < 2; ++s2) {
      int s = s2 * 256 + tid;          // 0..511: 16 b x 32 u
      int bl = s >> 5, uu = s & 31;
      size_t rowg = (size_t)(t * 64 + bg * 16 + bl);
      int gb = ug * 32 + uu;
      float gi = gbuf[0][bl][uu] + xp[rowg * 2048 + gb];
      float gf = gbuf[1][bl][uu] + xp[rowg * 2048 + 512 + gb];
      float gg = gbuf[2][bl][uu] + xp[rowg * 2048 + 1024 + gb];
      float go = gbuf[3][bl][uu] + xp[rowg * 2048 + 1536 + gb];
      float si = 1.f / (1.f + __expf(-gi));
      float sf = 1.f / (1.f + __expf(-gf));
      float so = 1.f / (1.f + __expf(-go));
      float c = sf * cst[s2] + si * tanhf(gg);
      cst[s2] = c;
      float h = so * tanhf(c);
      hseq[rowg * 512 + gb] = __float2bfloat16(h);
    }
    if (t < 31) grid_barrier(bar, 64u * (unsigned)(t + 1));
  }
}

extern "C" void kernel_launch(void* const* d_in, const int* in_sizes, int n_in,
                              void* d_out, int out_size, void* d_ws, size_t ws_size,
                              hipStream_t stream) {
  const float* feat = (const float*)d_in[0];   // [64,512]
  const int* caps   = (const int*)d_in[1];     // [64,32]
  const float* emb  = (const float*)d_in[2];   // [10000,512]
  const float* Wih  = (const float*)d_in[3];   // [2048,512]
  const float* Whh  = (const float*)d_in[4];   // [2048,512]
  const float* bih  = (const float*)d_in[5];   // [2048]
  const float* bhh  = (const float*)d_in[6];   // [2048]
  const float* fcW  = (const float*)d_in[7];   // [10000,512]
  const float* fcb  = (const float*)d_in[8];   // [10000]
  float* out = (float*)d_out;                  // [64,32,10000] fp32

  char* ws = (char*)d_ws;
  __hip_bfloat16* Xs   = (__hip_bfloat16*)(ws);                       // 2 MB [2048,512]
  __hip_bfloat16* WhhB = (__hip_bfloat16*)(ws + (size_t)2 * 1048576); // 2 MB [2048,512]
  float*          xprj = (float*)(ws + (size_t)4 * 1048576);          // 16 MB [2048,2048]
  __hip_bfloat16* hseq = (__hip_bfloat16*)(ws + (size_t)20 * 1048576);// 2 MB [2048,512]
  unsigned*       bar  = (unsigned*)(ws + (size_t)22 * 1048576);      // 64 B

  hipMemsetAsync(bar, 0, 64, stream);

  prep<<<1024, 256, 0, stream>>>(feat, caps, emb, Whh, Xs, WhhB);

  dim3 g1(16, 16);   // M=2048 (x), N=2048 (y)
  gemm_nt<<<g1, 256, 0, stream>>>(Xs, Wih, bih, bhh, xprj, 2048, 2048, 0);

  lstm_seq<<<64, 256, 0, stream>>>(xprj, WhhB, hseq, bar);

  dim3 g2(16, 79);   // M=2048 (x), N=10000 -> 79 col-tiles (y)
  gemm_nt<<<g2, 256, 0, stream>>>(hseq, fcW, fcb, nullptr, out, 10000, 10000, 1);
}

// Round 3
// 355.330 us; speedup vs baseline: 1.3899x; 1.3899x over previous
//
#include <hip/hip_runtime.h>
#include <hip/hip_bf16.h>
#include <stdint.h>

typedef __attribute__((ext_vector_type(8))) short short8;   // 8 bf16 in 4 VGPRs
typedef __attribute__((ext_vector_type(4))) float floatx4;
typedef unsigned long long ull;

__device__ __forceinline__ floatx4 mfma_bf16(short8 a, short8 b, floatx4 c) {
  return __builtin_amdgcn_mfma_f32_16x16x32_bf16(a, b, c, 0, 0, 0);
}

// async global->LDS, 16B per lane; lds must be the wave-uniform base (lane lands at +lane*16)
__device__ __forceinline__ void async16(const void* g, void* lds) {
  __builtin_amdgcn_global_load_lds(
      (const __attribute__((address_space(1))) unsigned int*)g,
      (__attribute__((address_space(3))) unsigned int*)lds, 16, 0, 0);
}

// convert 8 contiguous fp32 -> 8 bf16 (one 16B store)
__device__ __forceinline__ void cvt8_store(const float* __restrict__ src,
                                           __hip_bfloat16* __restrict__ dst) {
  float4 a = *(const float4*)src;
  float4 b = *(const float4*)(src + 4);
  __hip_bfloat16 t[8];
  t[0] = __float2bfloat16(a.x); t[1] = __float2bfloat16(a.y);
  t[2] = __float2bfloat16(a.z); t[3] = __float2bfloat16(a.w);
  t[4] = __float2bfloat16(b.x); t[5] = __float2bfloat16(b.y);
  t[6] = __float2bfloat16(b.z); t[7] = __float2bfloat16(b.w);
  *(uint4*)dst = *(const uint4*)t;
}

// ---------------- prep: r<2048 Xs gather | <4096 WhhB | <6144 WihB | else fcWB
__global__ __launch_bounds__(256) void prep(
    const float* __restrict__ feat, const int* __restrict__ caps,
    const float* __restrict__ emb,  const float* __restrict__ Whh,
    const float* __restrict__ Wih,  const float* __restrict__ fcW,
    __hip_bfloat16* __restrict__ Xs,   __hip_bfloat16* __restrict__ WhhB,
    __hip_bfloat16* __restrict__ WihB, __hip_bfloat16* __restrict__ fcWB) {
  int tid = blockIdx.x * 256 + threadIdx.x;
  int r = tid >> 6;
  int ch = (tid & 63) * 8;
  const float* src;
  __hip_bfloat16* dst;
  if (r < 2048) {
    int t = r >> 6, b = r & 63;
    bool i64 = (caps[1] == 0) & (caps[3] == 0) & (caps[5] == 0) & (caps[7] == 0) &
               (caps[9] == 0) & (caps[11] == 0) & (caps[13] == 0);
    if (t == 0) {
      src = feat + (size_t)b * 512 + ch;
    } else {
      int idx = i64 ? caps[(size_t)(b * 32 + t) * 2] : caps[b * 32 + t];
      idx = idx < 0 ? 0 : (idx > 9999 ? 9999 : idx);
      src = emb + (size_t)idx * 512 + ch;
    }
    dst = Xs + (size_t)r * 512 + ch;
  } else if (r < 4096) {
    src = Whh + (size_t)(r - 2048) * 512 + ch;  dst = WhhB + (size_t)(r - 2048) * 512 + ch;
  } else if (r < 6144) {
    src = Wih + (size_t)(r - 4096) * 512 + ch;  dst = WihB + (size_t)(r - 4096) * 512 + ch;
  } else {
    src = fcW + (size_t)(r - 6144) * 512 + ch;  dst = fcWB + (size_t)(r - 6144) * 512 + ch;
  }
  cvt8_store(src, dst);
}

// ---------------- NT GEMM: C[M x N] = A[M x 512](bf16) * B[N x 512]^T + bias
// bf16B: B already bf16 -> async global_load_lds staging; else fp32->bf16 cvt staging.
// mode 0: outF[row*ldc+col] = acc + b1[col] + b2[col]
// mode 1: outF[((row&63)*32+(row>>6))*ldc+col] = acc + b1[col]   (row = t*64+b -> [B,T,V])
__global__ __launch_bounds__(256) void gemm_nt(
    const __hip_bfloat16* __restrict__ A,
    const void* __restrict__ Bv,
    const float* __restrict__ b1,
    const float* __restrict__ b2,
    float* __restrict__ outF,
    int Nrows, int ldc, int mode, int bf16B) {
  const int K = 512;
  __shared__ __align__(16) __hip_bfloat16 As[128 * 32];
  __shared__ __align__(16) __hip_bfloat16 Bs[128 * 32];
  const int tid = threadIdx.x;
  const int ib = blockIdx.x, jb = blockIdx.y;
  const int w = tid >> 6, l = tid & 63, lr = l & 15, lq = l >> 4;
  const int wr = (w & 1) * 64, wc = (w >> 1) * 64;
  floatx4 acc[4][4] = {};
  for (int kt = 0; kt < 16; ++kt) {
    const int k0 = kt * 32;
#pragma unroll
    for (int it = 0; it < 2; ++it) {
      const int flat0 = it * 256 + w * 64;   // wave-uniform LDS base index
      const int flat = flat0 + l;
      const int row = flat >> 2, c8 = (flat & 3) * 8;
      async16(A + (size_t)(ib * 128 + row) * K + k0 + c8, As + flat0 * 8);
      int rb = jb * 128 + row;
      if (rb > Nrows - 1) rb = Nrows - 1;    // clamp tail (dup reads; cols guarded on store)
      if (bf16B) {
        async16((const __hip_bfloat16*)Bv + (size_t)rb * K + k0 + c8, Bs + flat0 * 8);
      } else {
        cvt8_store((const float*)Bv + (size_t)rb * K + k0 + c8, Bs + flat * 8);
      }
    }
    __syncthreads();
    short8 af[4], bfr[4];
#pragma unroll
    for (int mt = 0; mt < 4; ++mt)
      af[mt] = *(const short8*)(As + (wr + mt * 16 + lr) * 32 + lq * 8);
#pragma unroll
    for (int nt = 0; nt < 4; ++nt)
      bfr[nt] = *(const short8*)(Bs + (wc + nt * 16 + lr) * 32 + lq * 8);
#pragma unroll
    for (int mt = 0; mt < 4; ++mt)
#pragma unroll
      for (int nt = 0; nt < 4; ++nt)
        acc[mt][nt] = mfma_bf16(af[mt], bfr[nt], acc[mt][nt]);
    __syncthreads();
  }
#pragma unroll
  for (int mt = 0; mt < 4; ++mt) {
#pragma unroll
    for (int nt = 0; nt < 4; ++nt) {
      int col = jb * 128 + wc + nt * 16 + lr;
      if (col < Nrows) {
        float bias = b1[col] + (b2 ? b2[col] : 0.f);
#pragma unroll
        for (int r = 0; r < 4; ++r) {
          int row = ib * 128 + wr + mt * 16 + lq * 4 + r;
          size_t orow = mode ? (size_t)((row & 63) * 32 + (row >> 6)) : (size_t)row;
          outF[orow * ldc + col] = acc[mt][nt][r] + bias;
        }
      }
    }
  }
}

// ---------------- LSTM: 64 blocks (4 bg x 16 ug). Per-(bg,t) arrival counters (16
// producers) instead of a global barrier; h moves via relaxed agent-scope atomics
// (LLC write-through / LLC read — no wbl2/inv fences). Whh frags preloaded in regs.
__global__ __launch_bounds__(256, 1) void lstm_seq(
    const float* __restrict__ xp,            // [32][64][2048] fp32 (biases included)
    const __hip_bfloat16* __restrict__ Whh,  // [2048][512] bf16
    __hip_bfloat16* __restrict__ hseq,       // [32][64][512] bf16
    unsigned* __restrict__ cnt) {            // [32][4] counters, 128 B apart
  const int bg = blockIdx.x >> 4;   // 0..3  (16 batch rows)
  const int ug = blockIdx.x & 15;   // 0..15 (32 hidden units)
  const int tid = threadIdx.x;
  const int w = tid >> 6, l = tid & 63, lr = l & 15, lq = l >> 4;
  const int bl = tid >> 5, uu = tid & 31;
  __shared__ float gbuf[4][16][32];
  __shared__ __align__(8) __hip_bfloat16 hbuf[16][32];
  float c0 = 0.f, c1 = 0.f;

  // B fragments are constant across t: preload all 32 (128 VGPRs)
  short8 B0[16], B1[16];
  {
    const __hip_bfloat16* w0 = Whh + (size_t)(w * 512 + ug * 32 + lr) * 512 + lq * 8;
    const __hip_bfloat16* w1 = w0 + (size_t)16 * 512;
#pragma unroll
    for (int kk = 0; kk < 16; ++kk) {
      B0[kk] = *(const short8*)(w0 + kk * 32);
      B1[kk] = *(const short8*)(w1 + kk * 32);
    }
  }

  for (int t = 0; t < 32; ++t) {
    // prefetch this step's xp (independent of h) — in flight during the spin
    const float* xr0 = xp + ((size_t)t * 64 + bg * 16 + bl) * 2048 + ug * 32 + uu;
    const float* xr1 = xr0 + (size_t)8 * 2048;
    float xi0 = xr0[0], xf0 = xr0[512], xg0 = xr0[1024], xo0 = xr0[1536];
    float xi1 = xr1[0], xf1 = xr1[512], xg1 = xr1[1024], xo1 = xr1[1536];

    floatx4 a0 = {}, a1 = {};
    if (t > 0) {
      if (tid == 0) {
        const unsigned* f = cnt + ((t - 1) * 4 + bg) * 32;
        while (__hip_atomic_load(f, __ATOMIC_RELAXED, __HIP_MEMORY_SCOPE_AGENT) < 16u)
          __builtin_amdgcn_s_sleep(1);
      }
      __syncthreads();
      const ull* hp = (const ull*)(hseq + (size_t)((t - 1) * 64 + bg * 16 + lr) * 512);
#pragma unroll
      for (int kk = 0; kk < 16; ++kk) {
        union { ull u[2]; short8 v; } hv;
        hv.u[0] = __hip_atomic_load(hp + kk * 8 + lq * 2,
                                    __ATOMIC_RELAXED, __HIP_MEMORY_SCOPE_AGENT);
        hv.u[1] = __hip_atomic_load(hp + kk * 8 + lq * 2 + 1,
                                    __ATOMIC_RELAXED, __HIP_MEMORY_SCOPE_AGENT);
        a0 = mfma_bf16(hv.v, B0[kk], a0);
        a1 = mfma_bf16(hv.v, B1[kk], a1);
      }
    }
#pragma unroll
    for (int r = 0; r < 4; ++r) {
      gbuf[w][lq * 4 + r][lr] = a0[r];
      gbuf[w][lq * 4 + r][16 + lr] = a1[r];
    }
    __syncthreads();
    {
      float gi = gbuf[0][bl][uu] + xi0, gf = gbuf[1][bl][uu] + xf0;
      float gg = gbuf[2][bl][uu] + xg0, go = gbuf[3][bl][uu] + xo0;
      float c = 1.f / (1.f + __expf(-gf)) * c0 + 1.f / (1.f + __expf(-gi)) * tanhf(gg);
      c0 = c;
      hbuf[bl][uu] = __float2bfloat16(1.f / (1.f + __expf(-go)) * tanhf(c));
    }
    {
      float gi = gbuf[0][bl + 8][uu] + xi1, gf = gbuf[1][bl + 8][uu] + xf1;
      float gg = gbuf[2][bl + 8][uu] + xg1, go = gbuf[3][bl + 8][uu] + xo1;
      float c = 1.f / (1.f + __expf(-gf)) * c1 + 1.f / (1.f + __expf(-gi)) * tanhf(gg);
      c1 = c;
      hbuf[bl + 8][uu] = __float2bfloat16(1.f / (1.f + __expf(-go)) * tanhf(c));
    }
    __syncthreads();
    if (tid < 128) {   // 16 rows x 8 ull = our 16x32 h slice
      int r = tid >> 3, g = tid & 7;
      ull val = *(const ull*)(&hbuf[r][g * 4]);
      ull* dst = (ull*)(hseq + (size_t)(t * 64 + bg * 16 + r) * 512 + ug * 32) + g;
      __hip_atomic_store(dst, val, __ATOMIC_RELAXED, __HIP_MEMORY_SCOPE_AGENT);
    }
    __builtin_amdgcn_s_waitcnt(0);   // per-wave: h stores acked at LLC
    __syncthreads();                 // all waves done
    if (tid == 0)
      __hip_atomic_fetch_add(cnt + (t * 4 + bg) * 32, 1u,
                             __ATOMIC_RELAXED, __HIP_MEMORY_SCOPE_AGENT);
  }
}

extern "C" void kernel_launch(void* const* d_in, const int* in_sizes, int n_in,
                              void* d_out, int out_size, void* d_ws, size_t ws_size,
                              hipStream_t stream) {
  const float* feat = (const float*)d_in[0];
  const int* caps   = (const int*)d_in[1];
  const float* emb  = (const float*)d_in[2];
  const float* Wih  = (const float*)d_in[3];
  const float* Whh  = (const float*)d_in[4];
  const float* bih  = (const float*)d_in[5];
  const float* bhh  = (const float*)d_in[6];
  const float* fcW  = (const float*)d_in[7];
  const float* fcb  = (const float*)d_in[8];
  float* out = (float*)d_out;                  // [64,32,10000] fp32

  const size_t MB = 1048576;
  char* ws = (char*)d_ws;
  __hip_bfloat16* Xs   = (__hip_bfloat16*)(ws);             // 2 MB  [2048,512]
  __hip_bfloat16* WhhB = (__hip_bfloat16*)(ws + 2 * MB);    // 2 MB
  __hip_bfloat16* WihB = (__hip_bfloat16*)(ws + 4 * MB);    // 2 MB
  float*          xprj = (float*)(ws + 6 * MB);             // 16 MB [2048,2048]
  __hip_bfloat16* hseq = (__hip_bfloat16*)(ws + 22 * MB);   // 2 MB  [2048,512]
  unsigned*       cnt  = (unsigned*)(ws + 24 * MB);         // 16 KB [32][4] spaced
  __hip_bfloat16* fcWB = (__hip_bfloat16*)(ws + 24 * MB + 16384);  // 9.77 MB
  const size_t need = 24 * MB + 16384 + (size_t)10000 * 512 * 2;
  const int doFc = (ws_size >= need);

  hipMemsetAsync(cnt, 0, 16384, stream);

  int rows = doFc ? 16144 : 6144;   // Xs 2048 | WhhB 2048 | WihB 2048 | fcWB 10000
  prep<<<rows / 4, 256, 0, stream>>>(feat, caps, emb, Whh, Wih, fcW,
                                     Xs, WhhB, WihB, fcWB);

  gemm_nt<<<dim3(16, 16), 256, 0, stream>>>(Xs, WihB, bih, bhh, xprj,
                                            2048, 2048, 0, 1);

  lstm_seq<<<64, 256, 0, stream>>>(xprj, WhhB, hseq, cnt);

  if (doFc)
    gemm_nt<<<dim3(16, 79), 256, 0, stream>>>(hseq, fcWB, fcb, nullptr, out,
                                              10000, 10000, 1, 1);
  else
    gemm_nt<<<dim3(16, 79), 256, 0, stream>>>(hseq, fcW, fcb, nullptr, out,
                                              10000, 10000, 1, 0);
}